// Round 1
// baseline (7322.955 us; speedup 1.0000x reference)
//
#include <hip/hip_runtime.h>
#include <hip/hip_bf16.h>

// Problem constants
#define TT   4096      // B*S tokens
#define DM   4096      // model dim
#define NH   32        // q heads
#define NKV  8         // kv heads
#define HD   128       // head dim
#define SLEN 2048
#define NQKV 6144      // (NH + 2*NKV) * HD

// ---------------------------------------------------------------------------
// Kernel 1+4: fp32 NT GEMM  C[M][N] = A[M][K] * B[N][K]^T
// 128x128 tile, BK=8, 256 threads, 8x8 per-thread micro-tile.
// ---------------------------------------------------------------------------
#define BM 128
#define BN 128
#define BK 8

__global__ __launch_bounds__(256) void sgemm_nt(const float* __restrict__ A,
                                                const float* __restrict__ Bm,
                                                float* __restrict__ C,
                                                int M, int N, int K) {
    __shared__ float As[BK][BM];
    __shared__ float Bs[BK][BN];
    int tid = threadIdx.x;
    int bm = blockIdx.y * BM;
    int bn = blockIdx.x * BN;
    int lr = tid >> 1;          // 0..127 tile row
    int lk = (tid & 1) * 4;     // 0 or 4 (k offset)
    int ty = tid >> 4;          // 0..15
    int tx = tid & 15;          // 0..15

    float acc[8][8];
#pragma unroll
    for (int i = 0; i < 8; ++i)
#pragma unroll
        for (int j = 0; j < 8; ++j) acc[i][j] = 0.f;

    for (int k0 = 0; k0 < K; k0 += BK) {
        float4 av = *(const float4*)(A  + (size_t)(bm + lr) * K + k0 + lk);
        float4 bv = *(const float4*)(Bm + (size_t)(bn + lr) * K + k0 + lk);
        __syncthreads();
        As[lk + 0][lr] = av.x; As[lk + 1][lr] = av.y;
        As[lk + 2][lr] = av.z; As[lk + 3][lr] = av.w;
        Bs[lk + 0][lr] = bv.x; Bs[lk + 1][lr] = bv.y;
        Bs[lk + 2][lr] = bv.z; Bs[lk + 3][lr] = bv.w;
        __syncthreads();
#pragma unroll
        for (int kk = 0; kk < BK; ++kk) {
            float a[8], b[8];
            *(float4*)&a[0] = *(const float4*)&As[kk][ty * 8 + 0];
            *(float4*)&a[4] = *(const float4*)&As[kk][ty * 8 + 4];
            *(float4*)&b[0] = *(const float4*)&Bs[kk][tx * 8 + 0];
            *(float4*)&b[4] = *(const float4*)&Bs[kk][tx * 8 + 4];
#pragma unroll
            for (int i = 0; i < 8; ++i)
#pragma unroll
                for (int j = 0; j < 8; ++j)
                    acc[i][j] = fmaf(a[i], b[j], acc[i][j]);
        }
    }
#pragma unroll
    for (int i = 0; i < 8; ++i) {
        float4* cp = (float4*)(C + (size_t)(bm + ty * 8 + i) * N + bn + tx * 8);
        cp[0] = make_float4(acc[i][0], acc[i][1], acc[i][2], acc[i][3]);
        cp[1] = make_float4(acc[i][4], acc[i][5], acc[i][6], acc[i][7]);
    }
}

// ---------------------------------------------------------------------------
// Kernel 2: RoPE in-place on q (heads 0..31) and k (heads 32..39) of qkv.
// out[d]    = x1*c - x2*s ; out[d+64] = x2*c + x1*s  (c,s same for d,d+64)
// ---------------------------------------------------------------------------
__global__ __launch_bounds__(256) void rope_kernel(float* __restrict__ qkv,
                                                   const float* __restrict__ cosb,
                                                   const float* __restrict__ sinb) {
    int idx = blockIdx.x * blockDim.x + threadIdx.x;  // T * 40 * 64 threads
    int d = idx & 63;
    int h = (idx >> 6) % 40;
    int t = idx / (64 * 40);
    float* row = qkv + (size_t)t * NQKV + h * HD;
    float c0 = cosb[t * HD + d];
    float s0 = sinb[t * HD + d];
    float x1 = row[d];
    float x2 = row[d + 64];
    row[d]      = x1 * c0 - x2 * s0;
    row[d + 64] = x2 * c0 + x1 * s0;
}

// ---------------------------------------------------------------------------
// Kernel 3: causal GQA flash attention, fp32.
// Block = (q-tile of 32 rows, b*h). 256 threads: r = tid>>3 (q-row),
// cg = tid&7. Scores: kc = cg + 8j. Online softmax via width-8 shfl.
// ---------------------------------------------------------------------------
__global__ __launch_bounds__(256) void attn_kernel(const float* __restrict__ qkv,
                                                   float* __restrict__ ctx) {
    __shared__ float Qs[32][132];
    __shared__ float Ks[32][132];
    __shared__ float Vs[32][132];
    __shared__ float Ps[32][33];

    int tid = threadIdx.x;
    int qt = blockIdx.x;
    int bh = blockIdx.y;
    int b = bh >> 5;
    int h = bh & 31;
    int g = h >> 2;            // GQA group (H/KV = 4)
    int q0 = qt * 32;
    int r  = tid >> 3;         // 0..31  q-row within tile
    int cg = tid & 7;          // 0..7

    const size_t RS = NQKV;
    const float* qbase = qkv + (size_t)(b * SLEN + q0) * RS + h * HD;
    const float* kbase = qkv + (size_t)(b * SLEN) * RS + NH * HD + g * HD;
    const float* vbase = kbase + NKV * HD;

    // load Q tile
    {
        const float* src = qbase + (size_t)r * RS + cg * 16;
#pragma unroll
        for (int i = 0; i < 4; ++i)
            *(float4*)&Qs[r][cg * 16 + 4 * i] = ((const float4*)src)[i];
    }

    float m = -3.0e38f, l = 0.f;
    float acc[4][4];
#pragma unroll
    for (int j4 = 0; j4 < 4; ++j4)
#pragma unroll
        for (int e = 0; e < 4; ++e) acc[j4][e] = 0.f;

    const float scale = 0.08838834764831845f;  // 1/sqrt(128)
    int qi = q0 + r;
    int nkt = qt + 1;

    for (int kt = 0; kt < nkt; ++kt) {
        int k0 = kt * 32;
        __syncthreads();   // protect Ks/Vs/Ps from previous iteration
        {
            const float* ksrc = kbase + (size_t)(k0 + r) * RS + cg * 16;
            const float* vsrc = vbase + (size_t)(k0 + r) * RS + cg * 16;
#pragma unroll
            for (int i = 0; i < 4; ++i) {
                *(float4*)&Ks[r][cg * 16 + 4 * i] = ((const float4*)ksrc)[i];
                *(float4*)&Vs[r][cg * 16 + 4 * i] = ((const float4*)vsrc)[i];
            }
        }
        __syncthreads();

        // ---- scores: 4 per thread at kc = cg + 8j ----
        float s[4] = {0.f, 0.f, 0.f, 0.f};
#pragma unroll 4
        for (int d = 0; d < HD; d += 4) {
            float4 qv = *(const float4*)&Qs[r][d];
#pragma unroll
            for (int j = 0; j < 4; ++j) {
                float4 kv = *(const float4*)&Ks[cg + 8 * j][d];
                s[j] += qv.x * kv.x + qv.y * kv.y + qv.z * kv.z + qv.w * kv.w;
            }
        }
        float tm = -3.0e38f;
#pragma unroll
        for (int j = 0; j < 4; ++j) {
            int ki = k0 + cg + 8 * j;
            s[j] = (ki <= qi) ? s[j] * scale : -3.0e38f;
            tm = fmaxf(tm, s[j]);
        }
        // ---- online softmax (8 lanes own one row) ----
        tm = fmaxf(tm, __shfl_xor(tm, 1, 8));
        tm = fmaxf(tm, __shfl_xor(tm, 2, 8));
        tm = fmaxf(tm, __shfl_xor(tm, 4, 8));
        float mnew  = fmaxf(m, tm);
        float alpha = __expf(m - mnew);
        float ts = 0.f;
#pragma unroll
        for (int j = 0; j < 4; ++j) {
            float p = __expf(s[j] - mnew);
            s[j] = p;
            ts += p;
        }
        ts += __shfl_xor(ts, 1, 8);
        ts += __shfl_xor(ts, 2, 8);
        ts += __shfl_xor(ts, 4, 8);
        l = l * alpha + ts;
        m = mnew;
#pragma unroll
        for (int j = 0; j < 4; ++j) Ps[r][cg + 8 * j] = s[j];
        __syncthreads();

        // ---- PV: thread owns row r, d-cols cg*4 + 32*j4 ----
#pragma unroll
        for (int j4 = 0; j4 < 4; ++j4)
#pragma unroll
            for (int e = 0; e < 4; ++e) acc[j4][e] *= alpha;

        for (int kc = 0; kc < 32; ++kc) {
            float p = Ps[r][kc];
#pragma unroll
            for (int j4 = 0; j4 < 4; ++j4) {
                float4 vv = *(const float4*)&Vs[kc][cg * 4 + 32 * j4];
                acc[j4][0] = fmaf(p, vv.x, acc[j4][0]);
                acc[j4][1] = fmaf(p, vv.y, acc[j4][1]);
                acc[j4][2] = fmaf(p, vv.z, acc[j4][2]);
                acc[j4][3] = fmaf(p, vv.w, acc[j4][3]);
            }
        }
    }

    float inv = 1.0f / l;
    float* dst = ctx + (size_t)(b * SLEN + q0 + r) * DM + h * HD;
#pragma unroll
    for (int j4 = 0; j4 < 4; ++j4) {
        float4 o;
        o.x = acc[j4][0] * inv;
        o.y = acc[j4][1] * inv;
        o.z = acc[j4][2] * inv;
        o.w = acc[j4][3] * inv;
        *(float4*)&dst[cg * 4 + 32 * j4] = o;
    }
}

// ---------------------------------------------------------------------------
extern "C" void kernel_launch(void* const* d_in, const int* in_sizes, int n_in,
                              void* d_out, int out_size, void* d_ws, size_t ws_size,
                              hipStream_t stream) {
    const float* hs   = (const float*)d_in[0];  // (4096, 4096)
    const float* cosb = (const float*)d_in[1];  // (4096, 128)
    const float* sinb = (const float*)d_in[2];  // (4096, 128)
    const float* wqkv = (const float*)d_in[3];  // (6144, 4096)
    const float* wo   = (const float*)d_in[4];  // (4096, 4096)
    float* out = (float*)d_out;                 // (1, 4096, 4096)

    float* qkv = (float*)d_ws;                        // 4096 x 6144
    float* ctx = qkv + (size_t)TT * NQKV;             // 4096 x 4096

    dim3 blk(256);

    // 1) QKV = hidden @ Wqkv^T
    sgemm_nt<<<dim3(NQKV / BN, TT / BM), blk, 0, stream>>>(hs, wqkv, qkv, TT, NQKV, DM);

    // 2) RoPE on q,k heads in place
    {
        int total = TT * (NH + NKV) * (HD / 2);
        rope_kernel<<<total / 256, 256, 0, stream>>>(qkv, cosb, sinb);
    }

    // 3) causal GQA attention -> ctx
    attn_kernel<<<dim3(SLEN / 32, 2 * NH), blk, 0, stream>>>(qkv, ctx);

    // 4) out = ctx @ Wo^T
    sgemm_nt<<<dim3(DM / BN, TT / BM), blk, 0, stream>>>(ctx, wo, out, TT, DM, DM);
}

// Round 4
// 3871.055 us; speedup vs baseline: 1.8917x; 1.8917x over previous
//
#include <hip/hip_runtime.h>
#include <hip/hip_bf16.h>

// Problem constants
#define TT   4096      // B*S tokens
#define DM   4096      // model dim
#define NH   32        // q heads
#define NKV  8         // kv heads
#define HD   128       // head dim
#define SLEN 2048
#define NQKV 6144      // (NH + 2*NKV) * HD

typedef __bf16 bf16x4 __attribute__((ext_vector_type(4)));
typedef __bf16 bf16x8 __attribute__((ext_vector_type(8)));
typedef float  f32x4  __attribute__((ext_vector_type(4)));

// ---------------------------------------------------------------------------
// bf16-MFMA NT GEMM: C[M][N] = A[M][K] * B[N][K]^T, fp32 in/out, bf16 compute.
// 128x128 tile, BK=64, 256 threads (4 waves, 2x2), 4x4 16x16x32 frags/wave.
// fp32->bf16 conversion fused into LDS staging; XOR-swizzled LDS.
// ---------------------------------------------------------------------------
#define GBM 128
#define GBN 128
#define GBK 64

__global__ __launch_bounds__(256) void mfma_gemm_nt(const float* __restrict__ A,
                                                    const float* __restrict__ B,
                                                    float* __restrict__ C,
                                                    int M, int N, int K) {
    __shared__ __bf16 As[GBM * GBK];
    __shared__ __bf16 Bs[GBM * GBK];

    const int tid  = threadIdx.x;
    const int lane = tid & 63;

    // XCD-aware swizzle of linear block id (grids are multiples of 8)
    const int nwg = gridDim.x * gridDim.y;
    const int bid = blockIdx.y * gridDim.x + blockIdx.x;
    const int cpx = nwg >> 3;
    const int swz = (bid & 7) * cpx + (bid >> 3);
    const int bx = swz % gridDim.x;
    const int by = swz / gridDim.x;

    const size_t bm = (size_t)by * GBM;
    const size_t bn = (size_t)bx * GBN;

    // staging: thread covers rows srow0+16i (i=0..7), cols scol..scol+3 (fp32)
    // lanes 0..15 of each 16-thread group span one 256B-contiguous row chunk.
    const int srow0 = tid >> 4;          // 0..15
    const int scol  = (tid & 15) << 2;   // 0,4,...,60

    const float* Ag = A + (bm + srow0) * (size_t)K + scol;
    const float* Bg = B + (bn + srow0) * (size_t)K + scol;

    f32x4 pa[8], pb[8];
#pragma unroll
    for (int i = 0; i < 8; ++i) {
        pa[i] = *(const f32x4*)(Ag + (size_t)(16 * i) * K);
        pb[i] = *(const f32x4*)(Bg + (size_t)(16 * i) * K);
    }

    f32x4 acc[4][4];
#pragma unroll
    for (int m = 0; m < 4; ++m)
#pragma unroll
        for (int n = 0; n < 4; ++n)
#pragma unroll
            for (int r = 0; r < 4; ++r) acc[m][n][r] = 0.f;

    const int wid  = tid >> 6;
    const int wr   = wid >> 1;     // 0..1 : 64-row half
    const int wc   = wid & 1;      // 0..1 : 64-col half
    const int lrow = lane & 15;
    const int lkhi = lane >> 4;    // 0..3

    char* AsB = (char*)As;
    char* BsB = (char*)Bs;

    const int nk = K / GBK;
    for (int kt = 0; kt < nk; ++kt) {
        __syncthreads();
        // stage: convert fp32 regs -> bf16, swizzled ds_write_b64
#pragma unroll
        for (int i = 0; i < 8; ++i) {
            const int row = srow0 + 16 * i;
            bf16x4 wa, wb;
#pragma unroll
            for (int j = 0; j < 4; ++j) {
                wa[j] = (__bf16)pa[i][j];
                wb[j] = (__bf16)pb[i][j];
            }
            const int off = row * 128 + ((scol << 1) ^ ((row & 7) << 4));
            *(bf16x4*)(AsB + off) = wa;
            *(bf16x4*)(BsB + off) = wb;
        }
        __syncthreads();

        // prefetch next K-tile into regs (overlaps with MFMAs below)
        if (kt + 1 < nk) {
            Ag += GBK; Bg += GBK;
#pragma unroll
            for (int i = 0; i < 8; ++i) {
                pa[i] = *(const f32x4*)(Ag + (size_t)(16 * i) * K);
                pb[i] = *(const f32x4*)(Bg + (size_t)(16 * i) * K);
            }
        }

        // compute: 2 k-steps x 16 MFMAs
#pragma unroll
        for (int kk = 0; kk < 2; ++kk) {
            bf16x8 af[4], bfr[4];
#pragma unroll
            for (int m = 0; m < 4; ++m) {
                const int rowa = wr * 64 + m * 16 + lrow;
                af[m] = *(const bf16x8*)(AsB + rowa * 128 +
                         ((kk * 64 + lkhi * 16) ^ ((rowa & 7) << 4)));
                const int rowb = wc * 64 + m * 16 + lrow;
                bfr[m] = *(const bf16x8*)(BsB + rowb * 128 +
                         ((kk * 64 + lkhi * 16) ^ ((rowb & 7) << 4)));
            }
#pragma unroll
            for (int m = 0; m < 4; ++m)
#pragma unroll
                for (int n = 0; n < 4; ++n)
                    acc[m][n] = __builtin_amdgcn_mfma_f32_16x16x32_bf16(
                                    af[m], bfr[n], acc[m][n], 0, 0, 0);
        }
    }

    // C/D layout (m89): col = lane&15, row = (lane>>4)*4 + reg
    const int crow0 = wr * 64 + (lane >> 4) * 4;
    const int ccol0 = wc * 64 + (lane & 15);
#pragma unroll
    for (int m = 0; m < 4; ++m)
#pragma unroll
        for (int n = 0; n < 4; ++n) {
            float* cp = C + (bm + crow0 + m * 16) * (size_t)N + bn + ccol0 + n * 16;
#pragma unroll
            for (int r = 0; r < 4; ++r)
                cp[(size_t)r * N] = acc[m][n][r];
        }
}

// ---------------------------------------------------------------------------
// Kernel 2: RoPE in-place on q (heads 0..31) and k (heads 32..39) of qkv.
// ---------------------------------------------------------------------------
__global__ __launch_bounds__(256) void rope_kernel(float* __restrict__ qkv,
                                                   const float* __restrict__ cosb,
                                                   const float* __restrict__ sinb) {
    int idx = blockIdx.x * blockDim.x + threadIdx.x;
    int d = idx & 63;
    int h = (idx >> 6) % 40;
    int t = idx / (64 * 40);
    float* row = qkv + (size_t)t * NQKV + h * HD;
    float c0 = cosb[t * HD + d];
    float s0 = sinb[t * HD + d];
    float x1 = row[d];
    float x2 = row[d + 64];
    row[d]      = x1 * c0 - x2 * s0;
    row[d + 64] = x2 * c0 + x1 * s0;
}

// ---------------------------------------------------------------------------
// Kernel 3: causal GQA flash attention, fp32 (unchanged from round 1).
// ---------------------------------------------------------------------------
__global__ __launch_bounds__(256) void attn_kernel(const float* __restrict__ qkv,
                                                   float* __restrict__ ctx) {
    __shared__ float Qs[32][132];
    __shared__ float Ks[32][132];
    __shared__ float Vs[32][132];
    __shared__ float Ps[32][33];

    int tid = threadIdx.x;
    int qt = blockIdx.x;
    int bh = blockIdx.y;
    int b = bh >> 5;
    int h = bh & 31;
    int g = h >> 2;
    int q0 = qt * 32;
    int r  = tid >> 3;
    int cg = tid & 7;

    const size_t RS = NQKV;
    const float* qbase = qkv + (size_t)(b * SLEN + q0) * RS + h * HD;
    const float* kbase = qkv + (size_t)(b * SLEN) * RS + NH * HD + g * HD;
    const float* vbase = kbase + NKV * HD;

    {
        const float* src = qbase + (size_t)r * RS + cg * 16;
#pragma unroll
        for (int i = 0; i < 4; ++i)
            *(float4*)&Qs[r][cg * 16 + 4 * i] = ((const float4*)src)[i];
    }

    float m = -3.0e38f, l = 0.f;
    float acc[4][4];
#pragma unroll
    for (int j4 = 0; j4 < 4; ++j4)
#pragma unroll
        for (int e = 0; e < 4; ++e) acc[j4][e] = 0.f;

    const float scale = 0.08838834764831845f;
    int qi = q0 + r;
    int nkt = qt + 1;

    for (int kt = 0; kt < nkt; ++kt) {
        int k0 = kt * 32;
        __syncthreads();
        {
            const float* ksrc = kbase + (size_t)(k0 + r) * RS + cg * 16;
            const float* vsrc = vbase + (size_t)(k0 + r) * RS + cg * 16;
#pragma unroll
            for (int i = 0; i < 4; ++i) {
                *(float4*)&Ks[r][cg * 16 + 4 * i] = ((const float4*)ksrc)[i];
                *(float4*)&Vs[r][cg * 16 + 4 * i] = ((const float4*)vsrc)[i];
            }
        }
        __syncthreads();

        float s[4] = {0.f, 0.f, 0.f, 0.f};
#pragma unroll 4
        for (int d = 0; d < HD; d += 4) {
            float4 qv = *(const float4*)&Qs[r][d];
#pragma unroll
            for (int j = 0; j < 4; ++j) {
                float4 kv = *(const float4*)&Ks[cg + 8 * j][d];
                s[j] += qv.x * kv.x + qv.y * kv.y + qv.z * kv.z + qv.w * kv.w;
            }
        }
        float tm = -3.0e38f;
#pragma unroll
        for (int j = 0; j < 4; ++j) {
            int ki = k0 + cg + 8 * j;
            s[j] = (ki <= qi) ? s[j] * scale : -3.0e38f;
            tm = fmaxf(tm, s[j]);
        }
        tm = fmaxf(tm, __shfl_xor(tm, 1, 8));
        tm = fmaxf(tm, __shfl_xor(tm, 2, 8));
        tm = fmaxf(tm, __shfl_xor(tm, 4, 8));
        float mnew  = fmaxf(m, tm);
        float alpha = __expf(m - mnew);
        float ts = 0.f;
#pragma unroll
        for (int j = 0; j < 4; ++j) {
            float p = __expf(s[j] - mnew);
            s[j] = p;
            ts += p;
        }
        ts += __shfl_xor(ts, 1, 8);
        ts += __shfl_xor(ts, 2, 8);
        ts += __shfl_xor(ts, 4, 8);
        l = l * alpha + ts;
        m = mnew;
#pragma unroll
        for (int j = 0; j < 4; ++j) Ps[r][cg + 8 * j] = s[j];
        __syncthreads();

#pragma unroll
        for (int j4 = 0; j4 < 4; ++j4)
#pragma unroll
            for (int e = 0; e < 4; ++e) acc[j4][e] *= alpha;

        for (int kc = 0; kc < 32; ++kc) {
            float p = Ps[r][kc];
#pragma unroll
            for (int j4 = 0; j4 < 4; ++j4) {
                float4 vv = *(const float4*)&Vs[kc][cg * 4 + 32 * j4];
                acc[j4][0] = fmaf(p, vv.x, acc[j4][0]);
                acc[j4][1] = fmaf(p, vv.y, acc[j4][1]);
                acc[j4][2] = fmaf(p, vv.z, acc[j4][2]);
                acc[j4][3] = fmaf(p, vv.w, acc[j4][3]);
            }
        }
    }

    float inv = 1.0f / l;
    float* dst = ctx + (size_t)(b * SLEN + q0 + r) * DM + h * HD;
#pragma unroll
    for (int j4 = 0; j4 < 4; ++j4) {
        float4 o;
        o.x = acc[j4][0] * inv;
        o.y = acc[j4][1] * inv;
        o.z = acc[j4][2] * inv;
        o.w = acc[j4][3] * inv;
        *(float4*)&dst[cg * 4 + 32 * j4] = o;
    }
}

// ---------------------------------------------------------------------------
extern "C" void kernel_launch(void* const* d_in, const int* in_sizes, int n_in,
                              void* d_out, int out_size, void* d_ws, size_t ws_size,
                              hipStream_t stream) {
    const float* hs   = (const float*)d_in[0];  // (4096, 4096)
    const float* cosb = (const float*)d_in[1];  // (4096, 128)
    const float* sinb = (const float*)d_in[2];  // (4096, 128)
    const float* wqkv = (const float*)d_in[3];  // (6144, 4096)
    const float* wo   = (const float*)d_in[4];  // (4096, 4096)
    float* out = (float*)d_out;                 // (1, 4096, 4096)

    float* qkv = (float*)d_ws;                        // 4096 x 6144
    float* ctx = qkv + (size_t)TT * NQKV;             // 4096 x 4096

    dim3 blk(256);

    // 1) QKV = hidden @ Wqkv^T  (bf16 MFMA)
    mfma_gemm_nt<<<dim3(NQKV / GBN, TT / GBM), blk, 0, stream>>>(hs, wqkv, qkv, TT, NQKV, DM);

    // 2) RoPE on q,k heads in place (fp32)
    {
        int total = TT * (NH + NKV) * (HD / 2);
        rope_kernel<<<total / 256, 256, 0, stream>>>(qkv, cosb, sinb);
    }

    // 3) causal GQA attention -> ctx (fp32)
    attn_kernel<<<dim3(SLEN / 32, 2 * NH), blk, 0, stream>>>(qkv, ctx);

    // 4) out = ctx @ Wo^T  (bf16 MFMA)
    mfma_gemm_nt<<<dim3(DM / GBN, TT / GBM), blk, 0, stream>>>(ctx, wo, out, TT, DM, DM);
}

// Round 7
// 1467.035 us; speedup vs baseline: 4.9917x; 2.6387x over previous
//
#include <hip/hip_runtime.h>
#include <hip/hip_bf16.h>

// Problem constants
#define TT   4096      // B*S tokens
#define DM   4096      // model dim
#define NH   32        // q heads
#define NKV  8         // kv heads
#define HD   128       // head dim
#define SLEN 2048
#define NQKV 6144      // (NH + 2*NKV) * HD

typedef __bf16 bf16x4 __attribute__((ext_vector_type(4)));
typedef __bf16 bf16x8 __attribute__((ext_vector_type(8)));
typedef float  f32x4  __attribute__((ext_vector_type(4)));

// ---------------------------------------------------------------------------
// bf16-MFMA NT GEMM: C[M][N] = A[M][K] * B[N][K]^T, fp32 in, CT out.
// 128x128 tile, BK=64, 256 threads (4 waves, 2x2), 4x4 16x16x32 frags/wave.
// ---------------------------------------------------------------------------
#define GBM 128
#define GBN 128
#define GBK 64

template <typename CT>
__global__ __launch_bounds__(256) void mfma_gemm_nt(const float* __restrict__ A,
                                                    const float* __restrict__ B,
                                                    CT* __restrict__ C,
                                                    int M, int N, int K) {
    __shared__ __bf16 As[GBM * GBK];
    __shared__ __bf16 Bs[GBM * GBK];

    const int tid  = threadIdx.x;
    const int lane = tid & 63;

    const int nwg = gridDim.x * gridDim.y;
    const int bid = blockIdx.y * gridDim.x + blockIdx.x;
    const int cpx = nwg >> 3;
    const int swz = (bid & 7) * cpx + (bid >> 3);
    const int bx = swz % gridDim.x;
    const int by = swz / gridDim.x;

    const size_t bm = (size_t)by * GBM;
    const size_t bn = (size_t)bx * GBN;

    const int srow0 = tid >> 4;          // 0..15
    const int scol  = (tid & 15) << 2;   // 0,4,...,60

    const float* Ag = A + (bm + srow0) * (size_t)K + scol;
    const float* Bg = B + (bn + srow0) * (size_t)K + scol;

    f32x4 pa[8], pb[8];
#pragma unroll
    for (int i = 0; i < 8; ++i) {
        pa[i] = *(const f32x4*)(Ag + (size_t)(16 * i) * K);
        pb[i] = *(const f32x4*)(Bg + (size_t)(16 * i) * K);
    }

    f32x4 acc[4][4];
#pragma unroll
    for (int m = 0; m < 4; ++m)
#pragma unroll
        for (int n = 0; n < 4; ++n)
#pragma unroll
            for (int r = 0; r < 4; ++r) acc[m][n][r] = 0.f;

    const int wid  = tid >> 6;
    const int wr   = wid >> 1;
    const int wc   = wid & 1;
    const int lrow = lane & 15;
    const int lkhi = lane >> 4;

    char* AsB = (char*)As;
    char* BsB = (char*)Bs;

    const int nk = K / GBK;
    for (int kt = 0; kt < nk; ++kt) {
        __syncthreads();
#pragma unroll
        for (int i = 0; i < 8; ++i) {
            const int row = srow0 + 16 * i;
            bf16x4 wa, wb;
#pragma unroll
            for (int j = 0; j < 4; ++j) {
                wa[j] = (__bf16)pa[i][j];
                wb[j] = (__bf16)pb[i][j];
            }
            const int off = row * 128 + ((scol << 1) ^ ((row & 7) << 4));
            *(bf16x4*)(AsB + off) = wa;
            *(bf16x4*)(BsB + off) = wb;
        }
        __syncthreads();

        if (kt + 1 < nk) {
            Ag += GBK; Bg += GBK;
#pragma unroll
            for (int i = 0; i < 8; ++i) {
                pa[i] = *(const f32x4*)(Ag + (size_t)(16 * i) * K);
                pb[i] = *(const f32x4*)(Bg + (size_t)(16 * i) * K);
            }
        }

#pragma unroll
        for (int kk = 0; kk < 2; ++kk) {
            bf16x8 af[4], bfr[4];
#pragma unroll
            for (int m = 0; m < 4; ++m) {
                const int rowa = wr * 64 + m * 16 + lrow;
                af[m] = *(const bf16x8*)(AsB + rowa * 128 +
                         ((kk * 64 + lkhi * 16) ^ ((rowa & 7) << 4)));
                const int rowb = wc * 64 + m * 16 + lrow;
                bfr[m] = *(const bf16x8*)(BsB + rowb * 128 +
                         ((kk * 64 + lkhi * 16) ^ ((rowb & 7) << 4)));
            }
#pragma unroll
            for (int m = 0; m < 4; ++m)
#pragma unroll
                for (int n = 0; n < 4; ++n)
                    acc[m][n] = __builtin_amdgcn_mfma_f32_16x16x32_bf16(
                                    af[m], bfr[n], acc[m][n], 0, 0, 0);
        }
    }

    const int crow0 = wr * 64 + (lane >> 4) * 4;
    const int ccol0 = wc * 64 + (lane & 15);
#pragma unroll
    for (int m = 0; m < 4; ++m)
#pragma unroll
        for (int n = 0; n < 4; ++n) {
            CT* cp = C + (bm + crow0 + m * 16) * (size_t)N + bn + ccol0 + n * 16;
#pragma unroll
            for (int r = 0; r < 4; ++r)
                cp[(size_t)r * N] = (CT)acc[m][n][r];
        }
}

// ---------------------------------------------------------------------------
// RoPE in-place on bf16 qkv, q heads 0..31 and k heads 32..39. Vectorized x4.
// ---------------------------------------------------------------------------
__global__ __launch_bounds__(256) void rope_bf16(__bf16* __restrict__ qkv,
                                                 const float* __restrict__ cosb,
                                                 const float* __restrict__ sinb) {
    int idx = blockIdx.x * blockDim.x + threadIdx.x;
    int dg = idx & 15;                 // 16 groups of 4 d-pairs
    int h  = (idx >> 4) % 40;
    int t  = idx / (16 * 40);
    __bf16* row = qkv + (size_t)t * NQKV + h * HD;
    int d0 = dg * 4;
    bf16x4 x1 = *(bf16x4*)(row + d0);
    bf16x4 x2 = *(bf16x4*)(row + 64 + d0);
    f32x4 c = *(const f32x4*)(cosb + t * HD + d0);
    f32x4 s = *(const f32x4*)(sinb + t * HD + d0);
    bf16x4 o1, o2;
#pragma unroll
    for (int j = 0; j < 4; ++j) {
        float a = (float)x1[j], b = (float)x2[j];
        o1[j] = (__bf16)(a * c[j] - b * s[j]);
        o2[j] = (__bf16)(b * c[j] + a * s[j]);
    }
    *(bf16x4*)(row + d0) = o1;
    *(bf16x4*)(row + 64 + d0) = o2;
}

// ---------------------------------------------------------------------------
// bf16-MFMA causal GQA flash attention.
// Block: 256 thr = 4 waves; QBLK=64 (16 q-rows/wave), KVBLK=64.
// K in XOR-swizzled LDS [64][128]; V transposed [128][64] (swizzled);
// P via per-wave padded fp32 LDS. Online softmax in registers.
// ---------------------------------------------------------------------------
__global__ __launch_bounds__(256) void attn_mfma(const __bf16* __restrict__ qkv,
                                                 float* __restrict__ ctx) {
    __shared__ __bf16 Ks[64 * 128];
    __shared__ __bf16 Vt[128 * 64];
    __shared__ float  Ps[4 * 16 * 68];

    const int tid  = threadIdx.x;
    const int w    = tid >> 6;
    const int lane = tid & 63;
    const int lr   = lane & 15;     // frag row/col index
    const int lq   = lane >> 4;     // k-slot group / C-row quarter

    const int qt = gridDim.x - 1 - blockIdx.x;  // heavy blocks first
    const int bh = blockIdx.y;
    const int b = bh >> 5, h = bh & 31, g = h >> 2;
    const int q0 = qt * 64;

    // Q fragments in registers (A-operand layout: row=lr, k=lq*8+e)
    const __bf16* qrow = qkv + (size_t)(b * SLEN + q0 + w * 16 + lr) * NQKV + h * HD;
    bf16x8 qf[4];
#pragma unroll
    for (int kd = 0; kd < 4; ++kd)
        qf[kd] = *(const bf16x8*)(qrow + kd * 32 + lq * 8);

    f32x4 o[8];
    float m[4], l[4];
#pragma unroll
    for (int df = 0; df < 8; ++df)
#pragma unroll
        for (int r = 0; r < 4; ++r) o[df][r] = 0.f;
#pragma unroll
    for (int r = 0; r < 4; ++r) { m[r] = -3.0e38f; l[r] = 0.f; }

    char* KsB = (char*)Ks;
    char* VtB = (char*)Vt;
    float* Pw = Ps + w * 16 * 68;

    const int srow = tid >> 4;   // staging row 0..15
    const int sch  = tid & 15;   // staging chunk
    const __bf16* kglob = qkv + (size_t)(b * SLEN) * NQKV + (NH + g) * HD + sch * 8;
    const __bf16* vglob = qkv + (size_t)(b * SLEN) * NQKV + (NH + NKV + g) * HD + sch * 8;

    const float scale = 0.08838834764831845f;

    for (int kv0 = 0; kv0 <= q0; kv0 += 64) {
        __syncthreads();
        // ---- stage K (swizzled rows) and V (transposed, swizzled) ----
#pragma unroll
        for (int p = 0; p < 4; ++p) {
            const int k = p * 16 + srow;
            bf16x8 k8 = *(const bf16x8*)(kglob + (size_t)(kv0 + k) * NQKV);
            *(bf16x8*)(KsB + k * 256 + ((sch * 16) ^ ((k & 15) * 16))) = k8;
            bf16x8 v8 = *(const bf16x8*)(vglob + (size_t)(kv0 + k) * NQKV);
            const int d0 = sch * 8;
#pragma unroll
            for (int e = 0; e < 8; ++e) {
                const int d = d0 + e;
                *(__bf16*)(VtB + d * 128 + ((k * 2) ^ (((d >> 1) & 7) << 4))) = v8[e];
            }
        }
        __syncthreads();

        // ---- QK^T: S[16q x 64k] per wave ----
        f32x4 sacc[4];
#pragma unroll
        for (int n = 0; n < 4; ++n)
#pragma unroll
            for (int r = 0; r < 4; ++r) sacc[n][r] = 0.f;
#pragma unroll
        for (int kd = 0; kd < 4; ++kd) {
#pragma unroll
            for (int n = 0; n < 4; ++n) {
                const int row = n * 16 + lr;
                bf16x8 kf = *(const bf16x8*)(KsB + row * 256 +
                              (((kd * 4 + lq) * 16) ^ (lr * 16)));
                sacc[n] = __builtin_amdgcn_mfma_f32_16x16x32_bf16(
                              qf[kd], kf, sacc[n], 0, 0, 0);
            }
        }

        // ---- mask + online softmax (C layout: row=lq*4+r, col=lr+16n) ----
        float pv[4][4];
        float tm[4] = {-3.0e38f, -3.0e38f, -3.0e38f, -3.0e38f};
#pragma unroll
        for (int n = 0; n < 4; ++n)
#pragma unroll
            for (int r = 0; r < 4; ++r) {
                const int qi = q0 + w * 16 + lq * 4 + r;
                const int ki = kv0 + lr + 16 * n;
                const float s = (ki <= qi) ? sacc[n][r] * scale : -3.0e38f;
                pv[n][r] = s;
                tm[r] = fmaxf(tm[r], s);
            }
#pragma unroll
        for (int r = 0; r < 4; ++r) {
            tm[r] = fmaxf(tm[r], __shfl_xor(tm[r], 1));
            tm[r] = fmaxf(tm[r], __shfl_xor(tm[r], 2));
            tm[r] = fmaxf(tm[r], __shfl_xor(tm[r], 4));
            tm[r] = fmaxf(tm[r], __shfl_xor(tm[r], 8));
            const float mn = fmaxf(m[r], tm[r]);
            const float al = __expf(m[r] - mn);
            m[r] = mn;
            float t = 0.f;
#pragma unroll
            for (int n = 0; n < 4; ++n) {
                const float p = __expf(pv[n][r] - mn);
                pv[n][r] = p;
                t += p;
            }
            t += __shfl_xor(t, 1);
            t += __shfl_xor(t, 2);
            t += __shfl_xor(t, 4);
            t += __shfl_xor(t, 8);
            l[r] = l[r] * al + t;
#pragma unroll
            for (int df = 0; df < 8; ++df) o[df][r] *= al;
#pragma unroll
            for (int n = 0; n < 4; ++n)
                Pw[(lq * 4 + r) * 68 + lr + 16 * n] = pv[n][r];
        }

        // ---- PV: O[16q x 128d] += P[16x64] * V[64x128] ----
#pragma unroll
        for (int ks = 0; ks < 2; ++ks) {
            float a8[8];
            *(f32x4*)&a8[0] = *(const f32x4*)&Pw[lr * 68 + ks * 32 + lq * 8];
            *(f32x4*)&a8[4] = *(const f32x4*)&Pw[lr * 68 + ks * 32 + lq * 8 + 4];
            bf16x8 af;
#pragma unroll
            for (int e = 0; e < 8; ++e) af[e] = (__bf16)a8[e];
#pragma unroll
            for (int df = 0; df < 8; ++df) {
                const int d = df * 16 + lr;
                bf16x8 vf = *(const bf16x8*)(VtB + d * 128 +
                              (((ks * 4 + lq) * 16) ^ (((d >> 1) & 7) << 4)));
                o[df] = __builtin_amdgcn_mfma_f32_16x16x32_bf16(af, vf, o[df], 0, 0, 0);
            }
        }
    }

    // ---- epilogue ----
    float inv[4];
#pragma unroll
    for (int r = 0; r < 4; ++r) inv[r] = 1.0f / l[r];
#pragma unroll
    for (int df = 0; df < 8; ++df)
#pragma unroll
        for (int r = 0; r < 4; ++r) {
            const size_t row = (size_t)(b * SLEN + q0 + w * 16 + lq * 4 + r);
            ctx[row * DM + h * HD + df * 16 + lr] = o[df][r] * inv[r];
        }
}

// ---------------------------------------------------------------------------
extern "C" void kernel_launch(void* const* d_in, const int* in_sizes, int n_in,
                              void* d_out, int out_size, void* d_ws, size_t ws_size,
                              hipStream_t stream) {
    const float* hs   = (const float*)d_in[0];  // (4096, 4096)
    const float* cosb = (const float*)d_in[1];  // (4096, 128)
    const float* sinb = (const float*)d_in[2];  // (4096, 128)
    const float* wqkv = (const float*)d_in[3];  // (6144, 4096)
    const float* wo   = (const float*)d_in[4];  // (4096, 4096)
    float* out = (float*)d_out;                 // (1, 4096, 4096)

    __bf16* qkv = (__bf16*)d_ws;                                    // 4096 x 6144 bf16
    float*  ctx = (float*)((char*)d_ws + (size_t)TT * NQKV * 2);    // 4096 x 4096 f32

    dim3 blk(256);

    // 1) QKV = hidden @ Wqkv^T  (bf16 MFMA, bf16 out)
    mfma_gemm_nt<__bf16><<<dim3(NQKV / GBN, TT / GBM), blk, 0, stream>>>(
        hs, wqkv, qkv, TT, NQKV, DM);

    // 2) RoPE on q,k heads in place (bf16)
    rope_bf16<<<(TT * 40 * 16) / 256, 256, 0, stream>>>(qkv, cosb, sinb);

    // 3) causal GQA attention -> ctx (bf16 MFMA, fp32 out)
    attn_mfma<<<dim3(SLEN / 64, 2 * NH), blk, 0, stream>>>(qkv, ctx);

    // 4) out = ctx @ Wo^T  (bf16 MFMA, fp32 out)
    mfma_gemm_nt<float><<<dim3(DM / GBN, TT / GBM), blk, 0, stream>>>(
        ctx, wo, out, TT, DM, DM);
}

// Round 8
// 1358.039 us; speedup vs baseline: 5.3923x; 1.0803x over previous
//
#include <hip/hip_runtime.h>
#include <hip/hip_bf16.h>

// Problem constants
#define TT   4096      // B*S tokens
#define DM   4096      // model dim
#define NH   32        // q heads
#define NKV  8         // kv heads
#define HD   128       // head dim
#define SLEN 2048
#define NQKV 6144      // (NH + 2*NKV) * HD

typedef __bf16 bf16x2 __attribute__((ext_vector_type(2)));
typedef __bf16 bf16x4 __attribute__((ext_vector_type(4)));
typedef __bf16 bf16x8 __attribute__((ext_vector_type(8)));
typedef float  f32x4  __attribute__((ext_vector_type(4)));
typedef unsigned int u32;
typedef u32 u32x4 __attribute__((ext_vector_type(4)));

// Vt swizzle: XOR bits 4-6 of the within-row byte offset by (d&7)^((d>>3)&7).
// Write side (lanes vary d>>3=sch) and read side (lanes vary d&7=lr&7) both spread banks.
#define VSWZ(d) ((((d) & 7) ^ (((d) >> 3) & 7)) << 4)

// ---------------------------------------------------------------------------
// bf16-MFMA NT GEMM: C[M][N] = A[M][K] * B[N][K]^T, fp32 in, CT out.
// (unchanged from round 5 — validated)
// ---------------------------------------------------------------------------
#define GBM 128
#define GBN 128
#define GBK 64

template <typename CT>
__global__ __launch_bounds__(256) void mfma_gemm_nt(const float* __restrict__ A,
                                                    const float* __restrict__ B,
                                                    CT* __restrict__ C,
                                                    int M, int N, int K) {
    __shared__ __bf16 As[GBM * GBK];
    __shared__ __bf16 Bs[GBM * GBK];

    const int tid  = threadIdx.x;
    const int lane = tid & 63;

    const int nwg = gridDim.x * gridDim.y;
    const int bid = blockIdx.y * gridDim.x + blockIdx.x;
    const int cpx = nwg >> 3;
    const int swz = (bid & 7) * cpx + (bid >> 3);
    const int bx = swz % gridDim.x;
    const int by = swz / gridDim.x;

    const size_t bm = (size_t)by * GBM;
    const size_t bn = (size_t)bx * GBN;

    const int srow0 = tid >> 4;          // 0..15
    const int scol  = (tid & 15) << 2;   // 0,4,...,60

    const float* Ag = A + (bm + srow0) * (size_t)K + scol;
    const float* Bg = B + (bn + srow0) * (size_t)K + scol;

    f32x4 pa[8], pb[8];
#pragma unroll
    for (int i = 0; i < 8; ++i) {
        pa[i] = *(const f32x4*)(Ag + (size_t)(16 * i) * K);
        pb[i] = *(const f32x4*)(Bg + (size_t)(16 * i) * K);
    }

    f32x4 acc[4][4];
#pragma unroll
    for (int m = 0; m < 4; ++m)
#pragma unroll
        for (int n = 0; n < 4; ++n)
#pragma unroll
            for (int r = 0; r < 4; ++r) acc[m][n][r] = 0.f;

    const int wid  = tid >> 6;
    const int wr   = wid >> 1;
    const int wc   = wid & 1;
    const int lrow = lane & 15;
    const int lkhi = lane >> 4;

    char* AsB = (char*)As;
    char* BsB = (char*)Bs;

    const int nk = K / GBK;
    for (int kt = 0; kt < nk; ++kt) {
        __syncthreads();
#pragma unroll
        for (int i = 0; i < 8; ++i) {
            const int row = srow0 + 16 * i;
            bf16x4 wa, wb;
#pragma unroll
            for (int j = 0; j < 4; ++j) {
                wa[j] = (__bf16)pa[i][j];
                wb[j] = (__bf16)pb[i][j];
            }
            const int off = row * 128 + ((scol << 1) ^ ((row & 7) << 4));
            *(bf16x4*)(AsB + off) = wa;
            *(bf16x4*)(BsB + off) = wb;
        }
        __syncthreads();

        if (kt + 1 < nk) {
            Ag += GBK; Bg += GBK;
#pragma unroll
            for (int i = 0; i < 8; ++i) {
                pa[i] = *(const f32x4*)(Ag + (size_t)(16 * i) * K);
                pb[i] = *(const f32x4*)(Bg + (size_t)(16 * i) * K);
            }
        }

#pragma unroll
        for (int kk = 0; kk < 2; ++kk) {
            bf16x8 af[4], bfr[4];
#pragma unroll
            for (int m = 0; m < 4; ++m) {
                const int rowa = wr * 64 + m * 16 + lrow;
                af[m] = *(const bf16x8*)(AsB + rowa * 128 +
                         ((kk * 64 + lkhi * 16) ^ ((rowa & 7) << 4)));
                const int rowb = wc * 64 + m * 16 + lrow;
                bfr[m] = *(const bf16x8*)(BsB + rowb * 128 +
                         ((kk * 64 + lkhi * 16) ^ ((rowb & 7) << 4)));
            }
#pragma unroll
            for (int m = 0; m < 4; ++m)
#pragma unroll
                for (int n = 0; n < 4; ++n)
                    acc[m][n] = __builtin_amdgcn_mfma_f32_16x16x32_bf16(
                                    af[m], bfr[n], acc[m][n], 0, 0, 0);
        }
    }

    const int crow0 = wr * 64 + (lane >> 4) * 4;
    const int ccol0 = wc * 64 + (lane & 15);
#pragma unroll
    for (int m = 0; m < 4; ++m)
#pragma unroll
        for (int n = 0; n < 4; ++n) {
            CT* cp = C + (bm + crow0 + m * 16) * (size_t)N + bn + ccol0 + n * 16;
#pragma unroll
            for (int r = 0; r < 4; ++r)
                cp[(size_t)r * N] = (CT)acc[m][n][r];
        }
}

// ---------------------------------------------------------------------------
// RoPE in-place on bf16 qkv (unchanged from round 5 — validated)
// ---------------------------------------------------------------------------
__global__ __launch_bounds__(256) void rope_bf16(__bf16* __restrict__ qkv,
                                                 const float* __restrict__ cosb,
                                                 const float* __restrict__ sinb) {
    int idx = blockIdx.x * blockDim.x + threadIdx.x;
    int dg = idx & 15;
    int h  = (idx >> 4) % 40;
    int t  = idx / (16 * 40);
    __bf16* row = qkv + (size_t)t * NQKV + h * HD;
    int d0 = dg * 4;
    bf16x4 x1 = *(bf16x4*)(row + d0);
    bf16x4 x2 = *(bf16x4*)(row + 64 + d0);
    f32x4 c = *(const f32x4*)(cosb + t * HD + d0);
    f32x4 s = *(const f32x4*)(sinb + t * HD + d0);
    bf16x4 o1, o2;
#pragma unroll
    for (int j = 0; j < 4; ++j) {
        float a = (float)x1[j], b = (float)x2[j];
        o1[j] = (__bf16)(a * c[j] - b * s[j]);
        o2[j] = (__bf16)(b * c[j] + a * s[j]);
    }
    *(bf16x4*)(row + d0) = o1;
    *(bf16x4*)(row + 64 + d0) = o2;
}

// ---------------------------------------------------------------------------
// bf16-MFMA causal GQA flash attention, v2:
//  - swapped QK^T (S^T = mfma(K,Q)): softmax row lives in ONE lane (q=lr);
//    reduce = in-lane tree + 2 shuffles (was 32 shuffles).
//  - P kept in registers; P^T -> PV A-frag via bf16 packing + shfl permutation
//    (no Ps LDS round-trip).
//  - V^T staging via pair-shfl b32 writes + full-rank swizzle (was scalar
//    b16 scatter with 8-way conflicts = the measured 6.3e7).
//  - T14 async stage: next tile's global loads issued before compute barrier.
//  - LDS 32 KB -> 4 blocks/CU (was 50 KB -> 3).
// ---------------------------------------------------------------------------
__global__ __launch_bounds__(256) void attn_mfma(const __bf16* __restrict__ qkv,
                                                 float* __restrict__ ctx) {
    __shared__ __bf16 Ks[64 * 128];   // [kv][d], 16B-block swizzle by kv&15
    __shared__ __bf16 Vt[128 * 64];   // [d][kv], 16B-block swizzle VSWZ(d)

    const int tid  = threadIdx.x;
    const int w    = tid >> 6;
    const int lane = tid & 63;
    const int lr   = lane & 15;
    const int lq   = lane >> 4;

    const int qt = gridDim.x - 1 - blockIdx.x;  // heavy blocks first
    const int bh = blockIdx.y;
    const int b = bh >> 5, h = bh & 31, g = h >> 2;
    const int q0 = qt * 64;

    // Q fragment (used as mfma B-operand: col=q=lr, k=d=lq*8+e)
    const __bf16* qrow = qkv + (size_t)(b * SLEN + q0 + w * 16 + lr) * NQKV + h * HD;
    bf16x8 qf[4];
#pragma unroll
    for (int kd = 0; kd < 4; ++kd)
        qf[kd] = *(const bf16x8*)(qrow + kd * 32 + lq * 8);

    // O accumulator: o[df][r] = O[q = q0+w*16+lq*4+r][d = df*16+lr]
    f32x4 o[8];
#pragma unroll
    for (int df = 0; df < 8; ++df)
#pragma unroll
        for (int r = 0; r < 4; ++r) o[df][r] = 0.f;
    // online-softmax state for row q = q0+w*16+lr
    float m_ = -3.0e38f, l_ = 0.f;

    char* KsB = (char*)Ks;
    char* VtB = (char*)Vt;

    const int srow = tid >> 4;   // staging kv row 0..15 (per 16-group)
    const int sch  = tid & 15;   // staging d chunk
    const __bf16* kglob = qkv + (size_t)(b * SLEN) * NQKV + (NH + g) * HD + sch * 8;
    const __bf16* vglob = qkv + (size_t)(b * SLEN) * NQKV + (NH + NKV + g) * HD + sch * 8;

    const float scale = 0.08838834764831845f;
    const int qi_ = q0 + w * 16 + lr;
    const int sparity = srow & 1;

    // T14 prologue: preload tile 0 into registers
    bf16x8 kreg[4], vreg[4];
#pragma unroll
    for (int p = 0; p < 4; ++p) {
        kreg[p] = *(const bf16x8*)(kglob + (size_t)(p * 16 + srow) * NQKV);
        vreg[p] = *(const bf16x8*)(vglob + (size_t)(p * 16 + srow) * NQKV);
    }

    for (int kv0 = 0; kv0 <= q0; kv0 += 64) {
        __syncthreads();   // previous tile's LDS reads complete
        // ---- write staged K (vectorized, swizzled) ----
#pragma unroll
        for (int p = 0; p < 4; ++p) {
            const int k = p * 16 + srow;
            *(bf16x8*)(KsB + k * 256 + ((sch * 16) ^ ((k & 15) << 4))) = kreg[p];
        }
        // ---- write staged V transposed: pair-exchange + b32 kv-pair writes ----
#pragma unroll
        for (int p = 0; p < 4; ++p) {
            const int k  = p * 16 + srow;
            const int ke = k & ~1;
            u32x4 mine = __builtin_bit_cast(u32x4, vreg[p]);
            u32x4 part;
#pragma unroll
            for (int c = 0; c < 4; ++c) part[c] = __shfl_xor((int)mine[c], 16);
            bf16x8 vm = __builtin_bit_cast(bf16x8, mine);
            bf16x8 vp = __builtin_bit_cast(bf16x8, part);
#pragma unroll
            for (int jj = 0; jj < 4; ++jj) {
                const int j = sparity * 4 + jj;
                const int d = sch * 8 + j;
                bf16x2 val;
                val[0] = sparity ? vp[j] : vm[j];   // kv even
                val[1] = sparity ? vm[j] : vp[j];   // kv odd
                *(u32*)(VtB + d * 128 + ((ke * 2) ^ VSWZ(d))) =
                    __builtin_bit_cast(u32, val);
            }
        }
        // ---- T14: issue next tile's global loads (latency hides under compute)
        if (kv0 + 64 <= q0) {
#pragma unroll
            for (int p = 0; p < 4; ++p) {
                kreg[p] = *(const bf16x8*)(kglob + (size_t)(kv0 + 64 + p * 16 + srow) * NQKV);
                vreg[p] = *(const bf16x8*)(vglob + (size_t)(kv0 + 64 + p * 16 + srow) * NQKV);
            }
        }
        __syncthreads();   // LDS tile ready

        // ---- swapped QK^T: sacc[n] = S^T, rows kv=16n+lq*4+r, col q=lr ----
        f32x4 sacc[4];
#pragma unroll
        for (int n = 0; n < 4; ++n)
#pragma unroll
            for (int r = 0; r < 4; ++r) sacc[n][r] = 0.f;
#pragma unroll
        for (int kd = 0; kd < 4; ++kd) {
#pragma unroll
            for (int n = 0; n < 4; ++n) {
                const int row = n * 16 + lr;
                bf16x8 kf = *(const bf16x8*)(KsB + row * 256 +
                              (((kd * 4 + lq) * 16) ^ ((row & 15) << 4)));
                sacc[n] = __builtin_amdgcn_mfma_f32_16x16x32_bf16(
                              kf, qf[kd], sacc[n], 0, 0, 0);
            }
        }

        // ---- mask + in-register online softmax (row q=lr per lane) ----
        float p_[4][4];
#pragma unroll
        for (int n = 0; n < 4; ++n)
#pragma unroll
            for (int r = 0; r < 4; ++r) {
                const int ki = kv0 + 16 * n + lq * 4 + r;
                p_[n][r] = (ki <= qi_) ? sacc[n][r] * scale : -3.0e38f;
            }
        float rm[4];
#pragma unroll
        for (int n = 0; n < 4; ++n)
            rm[n] = fmaxf(fmaxf(p_[n][0], p_[n][1]), fmaxf(p_[n][2], p_[n][3]));
        float tm = fmaxf(fmaxf(rm[0], rm[1]), fmaxf(rm[2], rm[3]));
        tm = fmaxf(tm, __shfl_xor(tm, 16));
        tm = fmaxf(tm, __shfl_xor(tm, 32));
        const float mn = fmaxf(m_, tm);
        const float al = __expf(m_ - mn);
        m_ = mn;
        float rs[4];
#pragma unroll
        for (int n = 0; n < 4; ++n) {
#pragma unroll
            for (int r = 0; r < 4; ++r) {
                p_[n][r] = __expf(p_[n][r] - mn);
            }
            rs[n] = (p_[n][0] + p_[n][1]) + (p_[n][2] + p_[n][3]);
        }
        float ts = (rs[0] + rs[1]) + (rs[2] + rs[3]);
        ts += __shfl_xor(ts, 16);
        ts += __shfl_xor(ts, 32);
        l_ = l_ * al + ts;

        // rescale O rows (q = lq*4+r): fetch that row's alpha from lane lr=q
        float alr[4];
#pragma unroll
        for (int r = 0; r < 4; ++r)
            alr[r] = __shfl(al, (lane & 0x30) | (lq * 4 + r));
#pragma unroll
        for (int df = 0; df < 8; ++df)
#pragma unroll
            for (int r = 0; r < 4; ++r) o[df][r] *= alr[r];

        // ---- P^T -> PV A-fragments in registers ----
        // pack r-pairs to bf16x2: q32[n][j] = (P[lr][16n+lq*4+2j], ..+2j+1)
        u32 q32[4][2];
#pragma unroll
        for (int n = 0; n < 4; ++n)
#pragma unroll
            for (int j = 0; j < 2; ++j) {
                bf16x2 t;
                t[0] = (__bf16)p_[n][2 * j];
                t[1] = (__bf16)p_[n][2 * j + 1];
                q32[n][j] = __builtin_bit_cast(u32, t);
            }
        const int sA = (((2 * lq) & 3) << 4) | lr;
        const int sB = (((2 * lq + 1) & 3) << 4) | lr;
        const bool hi = (lq >> 1) != 0;

#pragma unroll
        for (int ks = 0; ks < 2; ++ks) {
            const u32 a0  = __shfl((int)q32[2 * ks][0],     sA);
            const u32 a0b = __shfl((int)q32[2 * ks + 1][0], sA);
            const u32 a1  = __shfl((int)q32[2 * ks][1],     sA);
            const u32 a1b = __shfl((int)q32[2 * ks + 1][1], sA);
            const u32 b0  = __shfl((int)q32[2 * ks][0],     sB);
            const u32 b0b = __shfl((int)q32[2 * ks + 1][0], sB);
            const u32 b1  = __shfl((int)q32[2 * ks][1],     sB);
            const u32 b1b = __shfl((int)q32[2 * ks + 1][1], sB);
            u32x4 wv;
            wv[0] = hi ? a0b : a0;
            wv[1] = hi ? a1b : a1;
            wv[2] = hi ? b0b : b0;
            wv[3] = hi ? b1b : b1;
            bf16x8 af = __builtin_bit_cast(bf16x8, wv);
            // PV: o[df] += P[q][kv] * V[kv][d]
#pragma unroll
            for (int df = 0; df < 8; ++df) {
                const int d = df * 16 + lr;
                bf16x8 vf = *(const bf16x8*)(VtB + d * 128 +
                              (((ks * 4 + lq) * 16) ^ VSWZ(d)));
                o[df] = __builtin_amdgcn_mfma_f32_16x16x32_bf16(af, vf, o[df], 0, 0, 0);
            }
        }
    }

    // ---- epilogue: rows q = lq*4+r use l from lane lr=q ----
    float linv[4];
#pragma unroll
    for (int r = 0; r < 4; ++r)
        linv[r] = 1.0f / __shfl(l_, (lane & 0x30) | (lq * 4 + r));
#pragma unroll
    for (int df = 0; df < 8; ++df)
#pragma unroll
        for (int r = 0; r < 4; ++r) {
            const size_t row = (size_t)(b * SLEN + q0 + w * 16 + lq * 4 + r);
            ctx[row * DM + h * HD + df * 16 + lr] = o[df][r] * linv[r];
        }
}

// ---------------------------------------------------------------------------
extern "C" void kernel_launch(void* const* d_in, const int* in_sizes, int n_in,
                              void* d_out, int out_size, void* d_ws, size_t ws_size,
                              hipStream_t stream) {
    const float* hs   = (const float*)d_in[0];  // (4096, 4096)
    const float* cosb = (const float*)d_in[1];  // (4096, 128)
    const float* sinb = (const float*)d_in[2];  // (4096, 128)
    const float* wqkv = (const float*)d_in[3];  // (6144, 4096)
    const float* wo   = (const float*)d_in[4];  // (4096, 4096)
    float* out = (float*)d_out;                 // (1, 4096, 4096)

    __bf16* qkv = (__bf16*)d_ws;                                    // 4096 x 6144 bf16
    float*  ctx = (float*)((char*)d_ws + (size_t)TT * NQKV * 2);    // 4096 x 4096 f32

    dim3 blk(256);

    // 1) QKV = hidden @ Wqkv^T  (bf16 MFMA, bf16 out)
    mfma_gemm_nt<__bf16><<<dim3(NQKV / GBN, TT / GBM), blk, 0, stream>>>(
        hs, wqkv, qkv, TT, NQKV, DM);

    // 2) RoPE on q,k heads in place (bf16)
    rope_bf16<<<(TT * 40 * 16) / 256, 256, 0, stream>>>(qkv, cosb, sinb);

    // 3) causal GQA attention -> ctx (bf16 MFMA, fp32 out)
    attn_mfma<<<dim3(SLEN / 64, 2 * NH), blk, 0, stream>>>(qkv, ctx);

    // 4) out = ctx @ Wo^T  (bf16 MFMA, fp32 out)
    mfma_gemm_nt<float><<<dim3(DM / GBN, TT / GBM), blk, 0, stream>>>(
        ctx, wo, out, TT, DM, DM);
}